// Round 4
// baseline (393.971 us; speedup 1.0000x reference)
//
#include <hip/hip_runtime.h>
#include <hip/hip_bf16.h>

// local_NCC_3d v4.
// k_pack: quad-duplicated image P4[g][h][w][d] = (v[d],v[d+1],v[w+1][d],v[w+1][d+1])
//         (border-clamped) so trilinear needs only 2 float4 gathers per group.
// K1: warp + 14 stat channels + 9-tap D box-sum + fused grad-L2.
// K2: W box-sum in-place, running-sum taps (23 LDS b128 reads vs 72).
// K3: H box-sum + cc, full-row staging with zero-filled halo, running-sum.
// K4: finalize.
// ws (P4 path): S[14*NVOX] f32 | P4[4*NVOX] float4 | pg2[8192] f64 | pcc[1024] f64
// Fallback (ws too small): direct-gather K1, no P4.

#define NVOX (128*128*128)   // 2^21
#define NGRP 4
#define NCH 14

// ------------------------------------------------ pack: img -> P4
__global__ __launch_bounds__(256) void k_pack(const float* __restrict__ img,
                                              float4* __restrict__ P4)
{
    int idx = blockIdx.x * 256 + threadIdx.x;       // over 4*NVOX
    int v = idx & (NVOX - 1);
    int g = idx >> 21;
    int d = v & 127;
    int w = (v >> 7) & 127;
    const float* im = img + (size_t)g * NVOX;
    int vd1 = (d < 127) ? v + 1 : v;
    int vw1 = (w < 127) ? v + 128 : v;
    int vw1d1 = (d < 127) ? vw1 + 1 : vw1;
    P4[idx] = make_float4(im[v], im[vd1], im[vw1], im[vw1d1]);
}

// ------------------------------------------------ K1 (P4 path)
__global__ __launch_bounds__(256) void k_warp_stats_p4(
    const float4* __restrict__ P4, const float* __restrict__ flo,
    float* __restrict__ S, double* __restrict__ pg2)
{
    __shared__ float jt[NGRP][256];
    int t = threadIdx.x;
    int v = blockIdx.x * 256 + t;
    int d = v & 127;
    int w = (v >> 7) & 127;
    int h = v >> 14;
    float g2s = 0.f;

#pragma unroll
    for (int g = 0; g < NGRP; ++g) {
        const float* f = flo + (size_t)g * 3 * NVOX;
        float fx = f[v], fy = f[NVOX + v], fz = f[2 * NVOX + v];
        if (h < 127) {
            float a = f[v + 16384] - fx;
            float b = f[NVOX + v + 16384] - fy;
            float c = f[2 * NVOX + v + 16384] - fz;
            g2s += a * a + b * b + c * c;
        }
        if (w < 127) {
            float a = f[v + 128] - fx;
            float b = f[NVOX + v + 128] - fy;
            float c = f[2 * NVOX + v + 128] - fz;
            g2s += a * a + b * b + c * c;
        }
        if (d < 127) {
            float a = f[v + 1] - fx;
            float b = f[NVOX + v + 1] - fy;
            float c = f[2 * NVOX + v + 1] - fz;
            g2s += a * a + b * b + c * c;
        }
        float ch = fminf(fmaxf(fx + (float)h, 0.f), 127.f);
        float cw = fminf(fmaxf(fy + (float)w, 0.f), 127.f);
        float cd = fminf(fmaxf(fz + (float)d, 0.f), 127.f);
        float h0f = floorf(ch), w0f = floorf(cw), d0f = floorf(cd);
        int h0 = (int)h0f, w0 = (int)w0f, d0 = (int)d0f;
        float fh = ch - h0f, fw = cw - w0f, fd = cd - d0f;
        int h1 = min(h0 + 1, 127);
        const float4* P = P4 + (size_t)g * NVOX;
        float4 q0 = P[h0 * 16384 + w0 * 128 + d0];
        float4 q1 = P[h1 * 16384 + w0 * 128 + d0];
        float c00 = q0.x + fd * (q0.y - q0.x);
        float c01 = q0.z + fd * (q0.w - q0.z);
        float c10 = q1.x + fd * (q1.y - q1.x);
        float c11 = q1.z + fd * (q1.w - q1.z);
        float c0 = c00 + fw * (c01 - c00);
        float c1 = c10 + fw * (c11 - c10);
        jt[g][t] = c0 + fh * (c1 - c0);
    }
    __syncthreads();

    float s[NCH];
#pragma unroll
    for (int c = 0; c < NCH; ++c) s[c] = 0.f;
    int lbase = t & 128;
#pragma unroll
    for (int k = -4; k <= 4; ++k) {
        int q = d + k;
        if ((unsigned)q < 128u) {
            int tq = lbase + q;
            float j0 = jt[0][tq], j1 = jt[1][tq], j2 = jt[2][tq], j3 = jt[3][tq];
            float tm = 0.25f * (j0 + j1 + j2 + j3);
            s[0] += tm;       s[1] += tm * tm;
            s[2] += j0;  s[3] += j0 * j0;  s[4]  += tm * j0;
            s[5] += j1;  s[6] += j1 * j1;  s[7]  += tm * j1;
            s[8] += j2;  s[9] += j2 * j2;  s[10] += tm * j2;
            s[11] += j3; s[12] += j3 * j3; s[13] += tm * j3;
        }
    }
#pragma unroll
    for (int c = 0; c < NCH; ++c) S[(size_t)c * NVOX + v] = s[c];

    double val = (double)g2s;
    for (int off = 32; off; off >>= 1) val += __shfl_down(val, off, 64);
    __shared__ double wsum[4];
    int lane = t & 63, wid = t >> 6;
    if (lane == 0) wsum[wid] = val;
    __syncthreads();
    if (t == 0) pg2[blockIdx.x] = wsum[0] + wsum[1] + wsum[2] + wsum[3];
}

// ------------------------------------------------ K1 (fallback: direct gathers)
__global__ __launch_bounds__(256) void k_warp_stats_direct(
    const float* __restrict__ img, const float* __restrict__ flo,
    float* __restrict__ S, double* __restrict__ pg2)
{
    __shared__ float jt[NGRP][256];
    int t = threadIdx.x;
    int v = blockIdx.x * 256 + t;
    int d = v & 127;
    int w = (v >> 7) & 127;
    int h = v >> 14;
    float g2s = 0.f;

#pragma unroll
    for (int g = 0; g < NGRP; ++g) {
        const float* f = flo + (size_t)g * 3 * NVOX;
        float fx = f[v], fy = f[NVOX + v], fz = f[2 * NVOX + v];
        if (h < 127) {
            float a = f[v + 16384] - fx;
            float b = f[NVOX + v + 16384] - fy;
            float c = f[2 * NVOX + v + 16384] - fz;
            g2s += a * a + b * b + c * c;
        }
        if (w < 127) {
            float a = f[v + 128] - fx;
            float b = f[NVOX + v + 128] - fy;
            float c = f[2 * NVOX + v + 128] - fz;
            g2s += a * a + b * b + c * c;
        }
        if (d < 127) {
            float a = f[v + 1] - fx;
            float b = f[NVOX + v + 1] - fy;
            float c = f[2 * NVOX + v + 1] - fz;
            g2s += a * a + b * b + c * c;
        }
        float ch = fminf(fmaxf(fx + (float)h, 0.f), 127.f);
        float cw = fminf(fmaxf(fy + (float)w, 0.f), 127.f);
        float cd = fminf(fmaxf(fz + (float)d, 0.f), 127.f);
        float h0f = floorf(ch), w0f = floorf(cw), d0f = floorf(cd);
        int h0 = (int)h0f, w0 = (int)w0f, d0 = (int)d0f;
        float fh = ch - h0f, fw = cw - w0f, fd = cd - d0f;
        int h1 = min(h0 + 1, 127), w1 = min(w0 + 1, 127), d1 = min(d0 + 1, 127);
        const float* im = img + (size_t)g * NVOX;
        int b00 = (h0 * 128 + w0) * 128;
        int b01 = (h0 * 128 + w1) * 128;
        int b10 = (h1 * 128 + w0) * 128;
        int b11 = (h1 * 128 + w1) * 128;
        float v000 = im[b00 + d0], v001 = im[b00 + d1];
        float v010 = im[b01 + d0], v011 = im[b01 + d1];
        float v100 = im[b10 + d0], v101 = im[b10 + d1];
        float v110 = im[b11 + d0], v111 = im[b11 + d1];
        float c00 = v000 + fd * (v001 - v000);
        float c01 = v010 + fd * (v011 - v010);
        float c10 = v100 + fd * (v101 - v100);
        float c11 = v110 + fd * (v111 - v110);
        float c0 = c00 + fw * (c01 - c00);
        float c1 = c10 + fw * (c11 - c10);
        jt[g][t] = c0 + fh * (c1 - c0);
    }
    __syncthreads();

    float s[NCH];
#pragma unroll
    for (int c = 0; c < NCH; ++c) s[c] = 0.f;
    int lbase = t & 128;
#pragma unroll
    for (int k = -4; k <= 4; ++k) {
        int q = d + k;
        if ((unsigned)q < 128u) {
            int tq = lbase + q;
            float j0 = jt[0][tq], j1 = jt[1][tq], j2 = jt[2][tq], j3 = jt[3][tq];
            float tm = 0.25f * (j0 + j1 + j2 + j3);
            s[0] += tm;       s[1] += tm * tm;
            s[2] += j0;  s[3] += j0 * j0;  s[4]  += tm * j0;
            s[5] += j1;  s[6] += j1 * j1;  s[7]  += tm * j1;
            s[8] += j2;  s[9] += j2 * j2;  s[10] += tm * j2;
            s[11] += j3; s[12] += j3 * j3; s[13] += tm * j3;
        }
    }
#pragma unroll
    for (int c = 0; c < NCH; ++c) S[(size_t)c * NVOX + v] = s[c];

    double val = (double)g2s;
    for (int off = 32; off; off >>= 1) val += __shfl_down(val, off, 64);
    __shared__ double wsum[4];
    int lane = t & 63, wid = t >> 6;
    if (lane == 0) wsum[wid] = val;
    __syncthreads();
    if (t == 0) pg2[blockIdx.x] = wsum[0] + wsum[1] + wsum[2] + wsum[3];
}

// ------------------------------------------------ K2: W box-sum, running-sum taps
__global__ __launch_bounds__(256) void k_sum_w(float* __restrict__ S)
{
    __shared__ float tile[128 * 64];                // [w][dd]
    int t = threadIdx.x;
    int bid = blockIdx.x;
    int half = bid & 1;
    int chh = bid >> 1;                             // c*128 + h
    size_t base = (size_t)chh * 16384 + half * 64;
#pragma unroll
    for (int it = 0; it < 8; ++it) {
        int idx4 = it * 256 + t;
        int w = idx4 >> 4, dq = idx4 & 15;
        *(float4*)(tile + w * 64 + dq * 4) =
            *(const float4*)(S + base + (size_t)w * 128 + dq * 4);
    }
    __syncthreads();
    int dq = t & 15;
    int wq = t >> 4;                                // 0..15, 8 w each
    int w0 = wq * 8;
    float4 s = make_float4(0.f, 0.f, 0.f, 0.f);
#pragma unroll
    for (int k = -4; k <= 4; ++k) {
        int q = w0 + k;
        if ((unsigned)q < 128u) {
            float4 tv = *(const float4*)(tile + q * 64 + dq * 4);
            s.x += tv.x; s.y += tv.y; s.z += tv.z; s.w += tv.w;
        }
    }
    *(float4*)(S + base + (size_t)w0 * 128 + dq * 4) = s;
#pragma unroll
    for (int wi = 1; wi < 8; ++wi) {
        int w = w0 + wi;
        int qa = w + 4;
        if (qa < 128) {
            float4 tv = *(const float4*)(tile + qa * 64 + dq * 4);
            s.x += tv.x; s.y += tv.y; s.z += tv.z; s.w += tv.w;
        }
        int qr = w - 5;
        if (qr >= 0) {
            float4 tv = *(const float4*)(tile + qr * 64 + dq * 4);
            s.x -= tv.x; s.y -= tv.y; s.z -= tv.z; s.w -= tv.w;
        }
        *(float4*)(S + base + (size_t)w * 128 + dq * 4) = s;
    }
}

// ------------------------------------------------ K3: H box-sum + cc (full rows)
__device__ __forceinline__ float cc4(float4 I, float4 I2, float4 J, float4 J2, float4 IJ)
{
    const float inv = 1.0f / 729.0f;
    float r = 0.f;
    {
        float cr = IJ.x - J.x * I.x * inv, iv = I2.x - I.x * I.x * inv, jv = J2.x - J.x * J.x * inv;
        r += cr * cr / (iv * jv + 1e-5f);
    }
    {
        float cr = IJ.y - J.y * I.y * inv, iv = I2.y - I.y * I.y * inv, jv = J2.y - J.y * J.y * inv;
        r += cr * cr / (iv * jv + 1e-5f);
    }
    {
        float cr = IJ.z - J.z * I.z * inv, iv = I2.z - I.z * I.z * inv, jv = J2.z - J.z * J.z * inv;
        r += cr * cr / (iv * jv + 1e-5f);
    }
    {
        float cr = IJ.w - J.w * I.w * inv, iv = I2.w - I.w * I.w * inv, jv = J2.w - J.w * J.w * inv;
        r += cr * cr / (iv * jv + 1e-5f);
    }
    return r;
}

#define LOADH(c, a0, a1)                                                       \
    do {                                                                       \
        const float* cp = S + (size_t)(c) * NVOX + cbase;                      \
        _Pragma("unroll")                                                      \
        for (int it = 0; it < 3; ++it) {                                       \
            int idx = it * 256 + t;                                            \
            if (idx < 640) {                    /* 40 rows x 16 quads */       \
                int row = idx >> 4, dqu = idx & 15;                            \
                int rr = r0 + row;                                             \
                float4 vv = make_float4(0.f, 0.f, 0.f, 0.f);                   \
                if ((unsigned)rr < 128u)                                       \
                    vv = *(const float4*)(cp + (size_t)rr * 16384 + dqu * 4);  \
                int la = row * 65 + dqu * 4;                                   \
                tile[la] = vv.x; tile[la + 1] = vv.y;                          \
                tile[la + 2] = vv.z; tile[la + 3] = vv.w;                      \
            }                                                                  \
        }                                                                      \
        __syncthreads();                                                       \
        {                                                                      \
            int hl = hg * 2;                                                   \
            float4 sum = make_float4(0.f, 0.f, 0.f, 0.f);                      \
            _Pragma("unroll")                                                  \
            for (int k = 0; k < 9; ++k) {                                      \
                const float* tp = tile + (hl + k) * 65 + dq * 4;               \
                sum.x += tp[0]; sum.y += tp[1]; sum.z += tp[2]; sum.w += tp[3];\
            }                                                                  \
            a0 = sum;                                                          \
            const float* ta = tile + (hl + 9) * 65 + dq * 4;                   \
            const float* tr = tile + hl * 65 + dq * 4;                         \
            sum.x += ta[0] - tr[0]; sum.y += ta[1] - tr[1];                    \
            sum.z += ta[2] - tr[2]; sum.w += ta[3] - tr[3];                    \
            a1 = sum;                                                          \
        }                                                                      \
        __syncthreads();                                                       \
    } while (0)

__global__ __launch_bounds__(256) void k_sum_h_cc(const float* __restrict__ S,
                                                  double* __restrict__ pcc)
{
    __shared__ float tile[40 * 65];                 // 10.4 KB
    int t = threadIdx.x;
    int bid = blockIdx.x;                           // 128w * 4hq * 2dh
    int dh = bid & 1;
    int hq = (bid >> 1) & 3;
    int w = bid >> 3;
    int r0 = hq * 32 - 4;                           // first staged global row
    size_t cbase = (size_t)w * 128 + dh * 64;
    int dq = t & 15;                                // d-quad within 64
    int hg = t >> 4;                                // 0..15, 2 h-outputs each

    float4 Ia0, Ia1, I2a0, I2a1, Ja0, Ja1, J2a0, J2a1, IJa0, IJa1;
    float lsum = 0.f;

    LOADH(0, Ia0, Ia1);
    LOADH(1, I2a0, I2a1);
    for (int g = 0; g < NGRP; ++g) {
        LOADH(2 + 3 * g, Ja0, Ja1);
        LOADH(3 + 3 * g, J2a0, J2a1);
        LOADH(4 + 3 * g, IJa0, IJa1);
        lsum += cc4(Ia0, I2a0, Ja0, J2a0, IJa0);
        lsum += cc4(Ia1, I2a1, Ja1, J2a1, IJa1);
    }

    double val = (double)lsum;
    for (int off = 32; off; off >>= 1) val += __shfl_down(val, off, 64);
    __shared__ double wsum[4];
    int lane = t & 63, wid = t >> 6;
    if (lane == 0) wsum[wid] = val;
    __syncthreads();
    if (t == 0) pcc[bid] = wsum[0] + wsum[1] + wsum[2] + wsum[3];
}

// ------------------------------------------------ K4: finalize
__global__ __launch_bounds__(256) void k_finalize(const double* __restrict__ pg2,
                                                  const double* __restrict__ pcc,
                                                  float* __restrict__ out)
{
    double s_cc = 0.0, s_g2 = 0.0;
    for (int i = threadIdx.x; i < 1024; i += 256) s_cc += pcc[i];
    for (int i = threadIdx.x; i < 8192; i += 256) s_g2 += pg2[i];
    for (int off = 32; off; off >>= 1) {
        s_cc += __shfl_down(s_cc, off, 64);
        s_g2 += __shfl_down(s_g2, off, 64);
    }
    __shared__ double a[4], b[4];
    int lane = threadIdx.x & 63, wid = threadIdx.x >> 6;
    if (lane == 0) { a[wid] = s_cc; b[wid] = s_g2; }
    __syncthreads();
    if (threadIdx.x == 0) {
        double cc_sum = a[0] + a[1] + a[2] + a[3];
        double g2_sum = b[0] + b[1] + b[2] + b[3];
        double lncc = -cc_sum / (4.0 * (double)NVOX);
        double g2 = g2_sum / (3.0 * 12.0 * 127.0 * 128.0 * 128.0);
        out[0] = (float)(lncc + g2);
    }
}

extern "C" void kernel_launch(void* const* d_in, const int* in_sizes, int n_in,
                              void* d_out, int out_size, void* d_ws, size_t ws_size,
                              hipStream_t stream)
{
    const float* img = (const float*)d_in[0];   // [4][1][128^3]
    const float* flo = (const float*)d_in[1];   // [4][3][128^3]
    float* out = (float*)d_out;

    const size_t S_BYTES  = (size_t)NCH * NVOX * 4;        // 117,440,512
    const size_t P4_BYTES = (size_t)NGRP * NVOX * 16;      // 134,217,728
    float* S = (float*)d_ws;

    if (ws_size >= S_BYTES + P4_BYTES + 8192 * 8 + 1024 * 8) {
        float4* P4 = (float4*)((char*)d_ws + S_BYTES);
        double* pg2 = (double*)((char*)d_ws + S_BYTES + P4_BYTES);
        double* pcc = pg2 + 8192;
        k_pack<<<(NGRP * NVOX) / 256, 256, 0, stream>>>(img, P4);
        k_warp_stats_p4<<<NVOX / 256, 256, 0, stream>>>(P4, flo, S, pg2);
        k_sum_w<<<NCH * 128 * 2, 256, 0, stream>>>(S);
        k_sum_h_cc<<<1024, 256, 0, stream>>>(S, pcc);
        k_finalize<<<1, 256, 0, stream>>>(pg2, pcc, out);
    } else {
        double* pg2 = (double*)((char*)d_ws + S_BYTES);
        double* pcc = pg2 + 8192;
        k_warp_stats_direct<<<NVOX / 256, 256, 0, stream>>>(img, flo, S, pg2);
        k_sum_w<<<NCH * 128 * 2, 256, 0, stream>>>(S);
        k_sum_h_cc<<<1024, 256, 0, stream>>>(S, pcc);
        k_finalize<<<1, 256, 0, stream>>>(pg2, pcc, out);
    }
}

// Round 5
// 351.476 us; speedup vs baseline: 1.1209x; 1.1209x over previous
//
#include <hip/hip_runtime.h>
#include <hip/hip_bf16.h>

// local_NCC_3d v5.
// K1: direct-gather warp + 14 stat channels + 9-tap D box-sum + fused grad-L2,
//     split into 4 quarter-launches (profiler visibility) with chunked XCD
//     swizzle (same-XCD blocks contiguous in (h,w) -> gather halo fits L2).
// K2: W box-sum in-place, running-sum taps, LDS stride 68.
// K3: H box-sum + cc, full-row staging with zero halo, running-sum.
// K4: finalize.
// ws: S[14*NVOX] f32 | pg2[8192] f64 | pcc[1024] f64.

#define NVOX (128*128*128)   // 2^21
#define NGRP 4
#define NCH 14

// ------------------------------------------------ K1: warp + stats + D-sum + g2
__global__ __launch_bounds__(256) void k_warp_stats_d(
    const float* __restrict__ img, const float* __restrict__ flo,
    float* __restrict__ S, double* __restrict__ pg2, int blk0)
{
    __shared__ float jt[NGRP][256];
    int t = threadIdx.x;
    // chunked XCD swizzle within this 2048-block quarter: XCD x gets 256
    // consecutive (h,w) blocks -> concurrent gather halo ~2.9MB <= 4MB L2.
    int b = blk0 + ((blockIdx.x & 7) << 8) + (blockIdx.x >> 3);
    int v = b * 256 + t;
    int d = v & 127;
    int w = (v >> 7) & 127;
    int h = v >> 14;
    float g2s = 0.f;

#pragma unroll
    for (int g = 0; g < NGRP; ++g) {
        const float* f = flo + (size_t)g * 3 * NVOX;
        float fx = f[v], fy = f[NVOX + v], fz = f[2 * NVOX + v];
        if (h < 127) {
            float a = f[v + 16384] - fx;
            float bb = f[NVOX + v + 16384] - fy;
            float c = f[2 * NVOX + v + 16384] - fz;
            g2s += a * a + bb * bb + c * c;
        }
        if (w < 127) {
            float a = f[v + 128] - fx;
            float bb = f[NVOX + v + 128] - fy;
            float c = f[2 * NVOX + v + 128] - fz;
            g2s += a * a + bb * bb + c * c;
        }
        if (d < 127) {
            float a = f[v + 1] - fx;
            float bb = f[NVOX + v + 1] - fy;
            float c = f[2 * NVOX + v + 1] - fz;
            g2s += a * a + bb * bb + c * c;
        }
        float ch = fminf(fmaxf(fx + (float)h, 0.f), 127.f);
        float cw = fminf(fmaxf(fy + (float)w, 0.f), 127.f);
        float cd = fminf(fmaxf(fz + (float)d, 0.f), 127.f);
        float h0f = floorf(ch), w0f = floorf(cw), d0f = floorf(cd);
        int h0 = (int)h0f, w0 = (int)w0f, d0 = (int)d0f;
        float fh = ch - h0f, fw = cw - w0f, fd = cd - d0f;
        int h1 = min(h0 + 1, 127), w1 = min(w0 + 1, 127), d1 = min(d0 + 1, 127);
        const float* im = img + (size_t)g * NVOX;
        int b00 = (h0 * 128 + w0) * 128;
        int b01 = (h0 * 128 + w1) * 128;
        int b10 = (h1 * 128 + w0) * 128;
        int b11 = (h1 * 128 + w1) * 128;
        float v000 = im[b00 + d0], v001 = im[b00 + d1];
        float v010 = im[b01 + d0], v011 = im[b01 + d1];
        float v100 = im[b10 + d0], v101 = im[b10 + d1];
        float v110 = im[b11 + d0], v111 = im[b11 + d1];
        float c00 = v000 + fd * (v001 - v000);
        float c01 = v010 + fd * (v011 - v010);
        float c10 = v100 + fd * (v101 - v100);
        float c11 = v110 + fd * (v111 - v110);
        float c0 = c00 + fw * (c01 - c00);
        float c1 = c10 + fw * (c11 - c10);
        jt[g][t] = c0 + fh * (c1 - c0);
    }
    __syncthreads();

    float s[NCH];
#pragma unroll
    for (int c = 0; c < NCH; ++c) s[c] = 0.f;
    int lbase = t & 128;
#pragma unroll
    for (int k = -4; k <= 4; ++k) {
        int q = d + k;
        if ((unsigned)q < 128u) {
            int tq = lbase + q;
            float j0 = jt[0][tq], j1 = jt[1][tq], j2 = jt[2][tq], j3 = jt[3][tq];
            float tm = 0.25f * (j0 + j1 + j2 + j3);
            s[0] += tm;       s[1] += tm * tm;
            s[2] += j0;  s[3] += j0 * j0;  s[4]  += tm * j0;
            s[5] += j1;  s[6] += j1 * j1;  s[7]  += tm * j1;
            s[8] += j2;  s[9] += j2 * j2;  s[10] += tm * j2;
            s[11] += j3; s[12] += j3 * j3; s[13] += tm * j3;
        }
    }
#pragma unroll
    for (int c = 0; c < NCH; ++c) S[(size_t)c * NVOX + v] = s[c];

    double val = (double)g2s;
    for (int off = 32; off; off >>= 1) val += __shfl_down(val, off, 64);
    __shared__ double wsum[4];
    int lane = t & 63, wid = t >> 6;
    if (lane == 0) wsum[wid] = val;
    __syncthreads();
    if (t == 0) pg2[b] = wsum[0] + wsum[1] + wsum[2] + wsum[3];
}

// ------------------------------------------------ K2: W box-sum, running-sum taps
__global__ __launch_bounds__(256) void k_sum_w(float* __restrict__ S)
{
    __shared__ float tile[128 * 68];                // [w][dd], stride 68 (pad)
    int t = threadIdx.x;
    int bid = blockIdx.x;
    int half = bid & 1;
    int chh = bid >> 1;                             // c*128 + h
    size_t base = (size_t)chh * 16384 + half * 64;
#pragma unroll
    for (int it = 0; it < 8; ++it) {
        int idx4 = it * 256 + t;
        int w = idx4 >> 4, dq = idx4 & 15;
        *(float4*)(tile + w * 68 + dq * 4) =
            *(const float4*)(S + base + (size_t)w * 128 + dq * 4);
    }
    __syncthreads();
    int dq = t & 15;
    int wq = t >> 4;                                // 0..15, 8 w each
    int w0 = wq * 8;
    float4 s = make_float4(0.f, 0.f, 0.f, 0.f);
#pragma unroll
    for (int k = -4; k <= 4; ++k) {
        int q = w0 + k;
        if ((unsigned)q < 128u) {
            float4 tv = *(const float4*)(tile + q * 68 + dq * 4);
            s.x += tv.x; s.y += tv.y; s.z += tv.z; s.w += tv.w;
        }
    }
    *(float4*)(S + base + (size_t)w0 * 128 + dq * 4) = s;
#pragma unroll
    for (int wi = 1; wi < 8; ++wi) {
        int w = w0 + wi;
        int qa = w + 4;
        if (qa < 128) {
            float4 tv = *(const float4*)(tile + qa * 68 + dq * 4);
            s.x += tv.x; s.y += tv.y; s.z += tv.z; s.w += tv.w;
        }
        int qr = w - 5;
        if (qr >= 0) {
            float4 tv = *(const float4*)(tile + qr * 68 + dq * 4);
            s.x -= tv.x; s.y -= tv.y; s.z -= tv.z; s.w -= tv.w;
        }
        *(float4*)(S + base + (size_t)w * 128 + dq * 4) = s;
    }
}

// ------------------------------------------------ K3: H box-sum + cc (full rows)
__device__ __forceinline__ float cc4(float4 I, float4 I2, float4 J, float4 J2, float4 IJ)
{
    const float inv = 1.0f / 729.0f;
    float r = 0.f;
    {
        float cr = IJ.x - J.x * I.x * inv, iv = I2.x - I.x * I.x * inv, jv = J2.x - J.x * J.x * inv;
        r += cr * cr / (iv * jv + 1e-5f);
    }
    {
        float cr = IJ.y - J.y * I.y * inv, iv = I2.y - I.y * I.y * inv, jv = J2.y - J.y * J.y * inv;
        r += cr * cr / (iv * jv + 1e-5f);
    }
    {
        float cr = IJ.z - J.z * I.z * inv, iv = I2.z - I.z * I.z * inv, jv = J2.z - J.z * J.z * inv;
        r += cr * cr / (iv * jv + 1e-5f);
    }
    {
        float cr = IJ.w - J.w * I.w * inv, iv = I2.w - I.w * I.w * inv, jv = J2.w - J.w * J.w * inv;
        r += cr * cr / (iv * jv + 1e-5f);
    }
    return r;
}

#define LOADH(c, a0, a1)                                                       \
    do {                                                                       \
        const float* cp = S + (size_t)(c) * NVOX + cbase;                      \
        _Pragma("unroll")                                                      \
        for (int it = 0; it < 3; ++it) {                                       \
            int idx = it * 256 + t;                                            \
            if (idx < 640) {                    /* 40 rows x 16 quads */       \
                int row = idx >> 4, dqu = idx & 15;                            \
                int rr = r0 + row;                                             \
                float4 vv = make_float4(0.f, 0.f, 0.f, 0.f);                   \
                if ((unsigned)rr < 128u)                                       \
                    vv = *(const float4*)(cp + (size_t)rr * 16384 + dqu * 4);  \
                int la = row * 65 + dqu * 4;                                   \
                tile[la] = vv.x; tile[la + 1] = vv.y;                          \
                tile[la + 2] = vv.z; tile[la + 3] = vv.w;                      \
            }                                                                  \
        }                                                                      \
        __syncthreads();                                                       \
        {                                                                      \
            int hl = hg * 2;                                                   \
            float4 sum = make_float4(0.f, 0.f, 0.f, 0.f);                      \
            _Pragma("unroll")                                                  \
            for (int k = 0; k < 9; ++k) {                                      \
                const float* tp = tile + (hl + k) * 65 + dq * 4;               \
                sum.x += tp[0]; sum.y += tp[1]; sum.z += tp[2]; sum.w += tp[3];\
            }                                                                  \
            a0 = sum;                                                          \
            const float* ta = tile + (hl + 9) * 65 + dq * 4;                   \
            const float* tr = tile + hl * 65 + dq * 4;                         \
            sum.x += ta[0] - tr[0]; sum.y += ta[1] - tr[1];                    \
            sum.z += ta[2] - tr[2]; sum.w += ta[3] - tr[3];                    \
            a1 = sum;                                                          \
        }                                                                      \
        __syncthreads();                                                       \
    } while (0)

__global__ __launch_bounds__(256) void k_sum_h_cc(const float* __restrict__ S,
                                                  double* __restrict__ pcc)
{
    __shared__ float tile[40 * 65];                 // 10.4 KB
    int t = threadIdx.x;
    int bid = blockIdx.x;                           // 128w * 4hq * 2dh
    int dh = bid & 1;
    int hq = (bid >> 1) & 3;
    int w = bid >> 3;
    int r0 = hq * 32 - 4;                           // first staged global row
    size_t cbase = (size_t)w * 128 + dh * 64;
    int dq = t & 15;                                // d-quad within 64
    int hg = t >> 4;                                // 0..15, 2 h-outputs each

    float4 Ia0, Ia1, I2a0, I2a1, Ja0, Ja1, J2a0, J2a1, IJa0, IJa1;
    float lsum = 0.f;

    LOADH(0, Ia0, Ia1);
    LOADH(1, I2a0, I2a1);
    for (int g = 0; g < NGRP; ++g) {
        LOADH(2 + 3 * g, Ja0, Ja1);
        LOADH(3 + 3 * g, J2a0, J2a1);
        LOADH(4 + 3 * g, IJa0, IJa1);
        lsum += cc4(Ia0, I2a0, Ja0, J2a0, IJa0);
        lsum += cc4(Ia1, I2a1, Ja1, J2a1, IJa1);
    }

    double val = (double)lsum;
    for (int off = 32; off; off >>= 1) val += __shfl_down(val, off, 64);
    __shared__ double wsum[4];
    int lane = t & 63, wid = t >> 6;
    if (lane == 0) wsum[wid] = val;
    __syncthreads();
    if (t == 0) pcc[bid] = wsum[0] + wsum[1] + wsum[2] + wsum[3];
}

// ------------------------------------------------ K4: finalize
__global__ __launch_bounds__(256) void k_finalize(const double* __restrict__ pg2,
                                                  const double* __restrict__ pcc,
                                                  float* __restrict__ out)
{
    double s_cc = 0.0, s_g2 = 0.0;
    for (int i = threadIdx.x; i < 1024; i += 256) s_cc += pcc[i];
    for (int i = threadIdx.x; i < 8192; i += 256) s_g2 += pg2[i];
    for (int off = 32; off; off >>= 1) {
        s_cc += __shfl_down(s_cc, off, 64);
        s_g2 += __shfl_down(s_g2, off, 64);
    }
    __shared__ double a[4], b[4];
    int lane = threadIdx.x & 63, wid = threadIdx.x >> 6;
    if (lane == 0) { a[wid] = s_cc; b[wid] = s_g2; }
    __syncthreads();
    if (threadIdx.x == 0) {
        double cc_sum = a[0] + a[1] + a[2] + a[3];
        double g2_sum = b[0] + b[1] + b[2] + b[3];
        double lncc = -cc_sum / (4.0 * (double)NVOX);
        double g2 = g2_sum / (3.0 * 12.0 * 127.0 * 128.0 * 128.0);
        out[0] = (float)(lncc + g2);
    }
}

extern "C" void kernel_launch(void* const* d_in, const int* in_sizes, int n_in,
                              void* d_out, int out_size, void* d_ws, size_t ws_size,
                              hipStream_t stream)
{
    const float* img = (const float*)d_in[0];   // [4][1][128^3]
    const float* flo = (const float*)d_in[1];   // [4][3][128^3]
    float* out = (float*)d_out;

    const size_t S_BYTES = (size_t)NCH * NVOX * 4;          // 117,440,512
    float* S = (float*)d_ws;
    double* pg2 = (double*)((char*)d_ws + S_BYTES);         // 8192 f64
    double* pcc = pg2 + 8192;                               // 1024 f64

    // K1 split into 4 quarter-launches for per-phase profiler visibility.
    k_warp_stats_d<<<2048, 256, 0, stream>>>(img, flo, S, pg2, 0);
    k_warp_stats_d<<<2048, 256, 0, stream>>>(img, flo, S, pg2, 2048);
    k_warp_stats_d<<<2048, 256, 0, stream>>>(img, flo, S, pg2, 4096);
    k_warp_stats_d<<<2048, 256, 0, stream>>>(img, flo, S, pg2, 6144);
    k_sum_w<<<NCH * 128 * 2, 256, 0, stream>>>(S);          // 3584 blocks
    k_sum_h_cc<<<1024, 256, 0, stream>>>(S, pcc);           // 128w*4hq*2dh
    k_finalize<<<1, 256, 0, stream>>>(pg2, pcc, out);
}